// Round 2
// baseline (1864.856 us; speedup 1.0000x reference)
//
#include <hip/hip_runtime.h>
#include <stdint.h>

// VQ: B=131072 rows, K=4096 codes, D=64, fp32 in/out.
// out = [B*D floats quantized_st][1 float loss]
//
// Strategy: bf16 split-precision MFMA distance search (3-product exact-split,
// error << flag threshold), per-row top-2 score tracking, fp32 full rescan of
// near-tie rows (expected ~5k of 131072).
constexpr int Bn = 131072, Kn = 4096, Dn = 64;
constexpr int NCHUNK = 256;          // K / 16 codes per chunk
constexpr float TAU_S = 0.075f;      // score-gap flag threshold (dist gap 0.15)

typedef short bf16x8 __attribute__((ext_vector_type(8)));
typedef float f32x4  __attribute__((ext_vector_type(4)));

__device__ __forceinline__ uint32_t rneb(float f) {           // bf16 RNE bits
    uint32_t u = __float_as_uint(f);
    return (u + 0x7FFFu + ((u >> 16) & 1u)) >> 16;
}
__device__ __forceinline__ float bfval(uint32_t b) { return __uint_as_float(b << 16); }

struct Split8 { bf16x8 hi, lo; };
// 8 floats -> bf16 hi (RNE) + bf16 lo (RNE of exact residual)
__device__ __forceinline__ Split8 split8(float4 a, float4 b) {
    uint32_t h0=rneb(a.x),h1=rneb(a.y),h2=rneb(a.z),h3=rneb(a.w);
    uint32_t h4=rneb(b.x),h5=rneb(b.y),h6=rneb(b.z),h7=rneb(b.w);
    uint32_t l0=rneb(a.x-bfval(h0)), l1=rneb(a.y-bfval(h1));
    uint32_t l2=rneb(a.z-bfval(h2)), l3=rneb(a.w-bfval(h3));
    uint32_t l4=rneb(b.x-bfval(h4)), l5=rneb(b.y-bfval(h5));
    uint32_t l6=rneb(b.z-bfval(h6)), l7=rneb(b.w-bfval(h7));
    union { bf16x8 v; uint32_t u[4]; } H, L;
    H.u[0]=h0|(h1<<16); H.u[1]=h2|(h3<<16); H.u[2]=h4|(h5<<16); H.u[3]=h6|(h7<<16);
    L.u[0]=l0|(l1<<16); L.u[1]=l2|(l3<<16); L.u[2]=l4|(l5<<16); L.u[3]=l6|(l7<<16);
    Split8 r; r.hi = H.v; r.lo = L.v; return r;
}

// ---- prep: codebook -> swizzled split-bf16 image (per 16-code chunk, 4KB) + -0.5|c|^2 ----
// image byte layout within chunk: for code j (0..15), virtual feature f (0..127;
// 0..63=hi, 64..127=lo): byte (j*256 + 2f) ^ ((j&7)<<4)
__global__ __launch_bounds__(256) void vq_prep(const float* __restrict__ cb,
                                               uint8_t* __restrict__ stage,
                                               float* __restrict__ negcn) {
    int t = blockIdx.x * 256 + threadIdx.x;     // 0..32767, one per 8 floats
    int code = t >> 3, oct = t & 7;
    const float4* cp = (const float4*)(cb + (size_t)code * Dn + oct * 8);
    float4 f0 = cp[0], f1 = cp[1];
    Split8 s = split8(f0, f1);
    int j = code & 15, cc = code >> 4;
    uint32_t swz = (uint32_t)((j & 7) << 4);
    uint8_t* base = stage + (size_t)cc * 4096;
    *(bf16x8*)(base + (((unsigned)(j*256 +       oct*16)) ^ swz)) = s.hi;
    *(bf16x8*)(base + (((unsigned)(j*256 + 128 + oct*16)) ^ swz)) = s.lo;
    float n = f0.x*f0.x + f0.y*f0.y + f0.z*f0.z + f0.w*f0.w
            + f1.x*f1.x + f1.y*f1.y + f1.z*f1.z + f1.w*f1.w;
    n += __shfl_xor(n, 1); n += __shfl_xor(n, 2); n += __shfl_xor(n, 4);
    if (oct == 0) negcn[code] = -0.5f * n;
}

__global__ void vq_zero(float* __restrict__ loss_acc, int* __restrict__ flag_cnt) {
    *loss_acc = 0.0f; *flag_cnt = 0;
}

__global__ __launch_bounds__(256, 2) void vq_main(
    const float* __restrict__ x, const uint8_t* __restrict__ stage,
    const float* __restrict__ negcn, const float* __restrict__ cb,
    float* __restrict__ out, float* __restrict__ loss_acc,
    int* __restrict__ flag_cnt, int* __restrict__ flag_rows) {

    __shared__ __align__(16) uint8_t sbuf[2][4096];  // chunk double buffer
    __shared__ float sneg[Kn];                       // -0.5|c|^2
    __shared__ int sres[256];

    const int tid = threadIdx.x;
    const int lane = tid & 63, w = tid >> 6;
    const int g = lane >> 4, j = lane & 15;

    #pragma unroll
    for (int i = 0; i < 16; ++i) sneg[i*256 + tid] = negcn[i*256 + tid];

    // x rows -> resident A fragments (A layout: row=lane&15, k=(lane>>4)*8+e)
    const int rowbase = blockIdx.x * 256 + w * 64;
    bf16x8 ah[4][2], al[4][2];
    #pragma unroll
    for (int t = 0; t < 4; ++t) {
        const float* xr = x + (size_t)(rowbase + t*16 + j) * Dn + g*8;
        Split8 s0 = split8(*(const float4*)xr,        *(const float4*)(xr + 4));
        Split8 s1 = split8(*(const float4*)(xr + 32), *(const float4*)(xr + 36));
        ah[t][0] = s0.hi; al[t][0] = s0.lo;
        ah[t][1] = s1.hi; al[t][1] = s1.lo;
    }

    auto issue_chunk = [&](int c) {   // one global_load_lds_dwordx4 per lane
        const uint8_t* src = stage + ((size_t)c << 12) + (w << 10) + (lane << 4);
        uint8_t* dst = &sbuf[c & 1][w << 10];
        __builtin_amdgcn_global_load_lds((const __attribute__((address_space(1))) void*)src,
                                         (__attribute__((address_space(3))) void*)dst,
                                         16, 0, 0);
    };

    // B-fragment byte offsets (code j, features g*8.. of {ch0,ch1,cl0,cl1})
    const uint32_t swz = (uint32_t)((j & 7) << 4);
    const int o0 = (int)(((unsigned)(j*256 +   0 + g*16)) ^ swz);
    const int o1 = (int)(((unsigned)(j*256 +  64 + g*16)) ^ swz);
    const int o2 = (int)(((unsigned)(j*256 + 128 + g*16)) ^ swz);
    const int o3 = (int)(((unsigned)(j*256 + 192 + g*16)) ^ swz);

    float b1[16], b2[16]; int bch[16];
    #pragma unroll
    for (int s = 0; s < 16; ++s) { b1[s] = -3.4e38f; b2[s] = -3.4e38f; bch[s] = 0; }

    issue_chunk(0);
    __syncthreads();

    for (int c = 0; c < NCHUNK; ++c) {
        if (c + 1 < NCHUNK) issue_chunk(c + 1);
        const uint8_t* bb = sbuf[c & 1];
        bf16x8 B0 = *(const bf16x8*)(bb + o0);
        bf16x8 B1 = *(const bf16x8*)(bb + o1);
        bf16x8 B2 = *(const bf16x8*)(bb + o2);
        bf16x8 B3 = *(const bf16x8*)(bb + o3);
        float nc = sneg[c*16 + j];
        #pragma unroll
        for (int t = 0; t < 4; ++t) {
            f32x4 acc = {nc, nc, nc, nc};     // score = dot - 0.5|c|^2
            acc = __builtin_amdgcn_mfma_f32_16x16x32_bf16(ah[t][0], B0, acc, 0, 0, 0);
            acc = __builtin_amdgcn_mfma_f32_16x16x32_bf16(ah[t][1], B1, acc, 0, 0, 0);
            acc = __builtin_amdgcn_mfma_f32_16x16x32_bf16(al[t][0], B0, acc, 0, 0, 0);
            acc = __builtin_amdgcn_mfma_f32_16x16x32_bf16(al[t][1], B1, acc, 0, 0, 0);
            acc = __builtin_amdgcn_mfma_f32_16x16x32_bf16(ah[t][0], B2, acc, 0, 0, 0);
            acc = __builtin_amdgcn_mfma_f32_16x16x32_bf16(ah[t][1], B3, acc, 0, 0, 0);
            #pragma unroll
            for (int q = 0; q < 4; ++q) {
                int s = t*4 + q;
                float v = acc[q];
                float ob1 = b1[s];
                b2[s] = fmaxf(fminf(v, ob1), b2[s]);   // second-best (med3)
                bch[s] = (v > ob1) ? c : bch[s];
                b1[s] = fmaxf(v, ob1);
            }
        }
        __syncthreads();
    }

    // per-row merge across 16 col-slot lanes (D layout: row=(lane>>4)*4+q, col=lane&15)
    #pragma unroll
    for (int s = 0; s < 16; ++s) {
        float v1 = b1[s], v2 = b2[s];
        int kk = bch[s] * 16 + j;
        #pragma unroll
        for (int m = 1; m < 16; m <<= 1) {
            float p1 = __shfl_xor(v1, m);
            float p2 = __shfl_xor(v2, m);
            int pk = __shfl_xor(kk, m);
            v2 = fmaxf(fmaxf(v2, p2), fminf(v1, p1));
            bool take = (p1 > v1) || ((p1 == v1) && (pk < kk));
            v1 = take ? p1 : v1;
            kk = take ? pk : kk;
        }
        if (j == 0) {
            int flag = ((v1 - v2) < TAU_S) ? (int)0x80000000 : 0;
            sres[w*64 + (s >> 2)*16 + g*4 + (s & 3)] = kk | flag;
        }
    }
    __syncthreads();

    // epilogue: gather, straight-through out, loss; flag near-ties for rescan
    int pk = sres[tid];
    int idx = pk & 0x7FFFFFFF;
    bool flagged = pk < 0;
    size_t grow = (size_t)blockIdx.x * 256 + tid;
    const float4* xr2 = (const float4*)(x + grow * Dn);
    const float4* qr  = (const float4*)(cb + (size_t)idx * Dn);
    float4* orow = (float4*)(out + grow * Dn);
    float ls = 0.f;
    #pragma unroll
    for (int t2 = 0; t2 < 16; ++t2) {
        float4 xx = xr2[t2], qq = qr[t2];
        float dx = qq.x - xx.x, dy = qq.y - xx.y, dz = qq.z - xx.z, dw = qq.w - xx.w;
        float4 o; o.x = xx.x + dx; o.y = xx.y + dy; o.z = xx.z + dz; o.w = xx.w + dw;
        orow[t2] = o;
        ls = fmaf(dx, dx, ls); ls = fmaf(dy, dy, ls);
        ls = fmaf(dz, dz, ls); ls = fmaf(dw, dw, ls);
    }
    if (flagged) {
        ls = 0.f;
        int p = atomicAdd(flag_cnt, 1);
        flag_rows[p] = (int)grow;
    }
    #pragma unroll
    for (int m = 1; m < 64; m <<= 1) ls += __shfl_xor(ls, m);
    if (lane == 0) atomicAdd(loss_acc, ls);
}

// fp32 full rescan of flagged rows (round-0 arithmetic; expected few thousand rows)
__global__ __launch_bounds__(256) void vq_cleanup(
    const float* __restrict__ x, const float* __restrict__ cb,
    const float* __restrict__ negcn, const int* __restrict__ flag_cnt,
    const int* __restrict__ flag_rows, float* __restrict__ out,
    float* __restrict__ loss_acc) {
    int i = blockIdx.x * 256 + threadIdx.x;
    int n = *flag_cnt;
    float ls = 0.f;
    if (i < n) {
        int row = flag_rows[i];
        const float4* xr = (const float4*)(x + (size_t)row * Dn);
        float4 xv[16];
        #pragma unroll
        for (int t = 0; t < 16; ++t) xv[t] = xr[t];
        float best = 3.4e38f; int bidx = 0;
        for (int k = 0; k < Kn; ++k) {
            const float4* c4 = (const float4*)(cb + (size_t)k * Dn);
            float a0 = 0.f, a1 = 0.f, a2 = 0.f, a3 = 0.f;
            #pragma unroll
            for (int t = 0; t < 16; ++t) {
                float4 c = c4[t];
                a0 = fmaf(xv[t].x, c.x, a0);
                a1 = fmaf(xv[t].y, c.y, a1);
                a2 = fmaf(xv[t].z, c.z, a2);
                a3 = fmaf(xv[t].w, c.w, a3);
            }
            float cn = -2.0f * negcn[k];
            float d = fmaf(-2.0f, (a0 + a1) + (a2 + a3), cn);
            if (d < best) { best = d; bidx = k; }     // strict <: first occurrence
        }
        const float4* qr = (const float4*)(cb + (size_t)bidx * Dn);
        float4* orow = (float4*)(out + (size_t)row * Dn);
        #pragma unroll
        for (int t = 0; t < 16; ++t) {
            float4 xx = xv[t], qq = qr[t];
            float dx = qq.x - xx.x, dy = qq.y - xx.y, dz = qq.z - xx.z, dw = qq.w - xx.w;
            float4 o; o.x = xx.x + dx; o.y = xx.y + dy; o.z = xx.z + dz; o.w = xx.w + dw;
            orow[t] = o;
            ls = fmaf(dx, dx, ls); ls = fmaf(dy, dy, ls);
            ls = fmaf(dz, dz, ls); ls = fmaf(dw, dw, ls);
        }
    }
    #pragma unroll
    for (int m = 1; m < 64; m <<= 1) ls += __shfl_xor(ls, m);
    if ((threadIdx.x & 63) == 0 && ls != 0.f) atomicAdd(loss_acc, ls);
}

__global__ void vq_final(float* __restrict__ loss_acc) {
    *loss_acc = *loss_acc * (1.25f / (float)(Bn * Dn));
}

extern "C" void kernel_launch(void* const* d_in, const int* in_sizes, int n_in,
                              void* d_out, int out_size, void* d_ws, size_t ws_size,
                              hipStream_t stream) {
    const float* x  = (const float*)d_in[0];
    const float* cb = (const float*)d_in[1];
    float* out  = (float*)d_out;
    float* loss = out + (size_t)Bn * Dn;

    // ws layout: [negcn 16KB][stage 1MB][flag_cnt 4B][flag_rows 512KB] = ~1.6MB
    uint8_t* wsb = (uint8_t*)d_ws;
    float*   negcn     = (float*)wsb;
    uint8_t* stage     = wsb + 16384;
    int*     flag_cnt  = (int*)(wsb + 16384 + (size_t)NCHUNK * 4096);
    int*     flag_rows = flag_cnt + 1;

    vq_prep<<<128, 256, 0, stream>>>(cb, stage, negcn);
    vq_zero<<<1, 1, 0, stream>>>(loss, flag_cnt);
    vq_main<<<512, 256, 0, stream>>>(x, stage, negcn, cb, out, loss, flag_cnt, flag_rows);
    vq_cleanup<<<512, 256, 0, stream>>>(x, cb, negcn, flag_cnt, flag_rows, out, loss);
    vq_final<<<1, 1, 0, stream>>>(loss);
}

// Round 3
// 477.826 us; speedup vs baseline: 3.9028x; 3.9028x over previous
//
#include <hip/hip_runtime.h>
#include <stdint.h>

// VQ: B=131072 rows, K=4096 codes, D=64, fp32 in/out.
// out = [B*D floats quantized_st][1 float loss]
//
// Strategy: bf16 split-precision MFMA distance search (3-product exact-split,
// worst-case score error ~1e-3), per-row top-2 score tracking, fp32 full
// rescan of near-tie rows (TAU_S=0.02 -> expected ~1k of 131072 rows),
// cleanup parallelized one-block-per-row.
constexpr int Bn = 131072, Kn = 4096, Dn = 64;
constexpr int NCHUNK = 256;          // K / 16 codes per chunk
constexpr float TAU_S = 0.02f;       // score-gap flag threshold (20x error bound)

typedef short bf16x8 __attribute__((ext_vector_type(8)));
typedef float f32x4  __attribute__((ext_vector_type(4)));

__device__ __forceinline__ uint32_t rneb(float f) {           // bf16 RNE bits
    uint32_t u = __float_as_uint(f);
    return (u + 0x7FFFu + ((u >> 16) & 1u)) >> 16;
}
__device__ __forceinline__ float bfval(uint32_t b) { return __uint_as_float(b << 16); }

struct Split8 { bf16x8 hi, lo; };
// 8 floats -> bf16 hi (RNE) + bf16 lo (RNE of exact residual)
__device__ __forceinline__ Split8 split8(float4 a, float4 b) {
    uint32_t h0=rneb(a.x),h1=rneb(a.y),h2=rneb(a.z),h3=rneb(a.w);
    uint32_t h4=rneb(b.x),h5=rneb(b.y),h6=rneb(b.z),h7=rneb(b.w);
    uint32_t l0=rneb(a.x-bfval(h0)), l1=rneb(a.y-bfval(h1));
    uint32_t l2=rneb(a.z-bfval(h2)), l3=rneb(a.w-bfval(h3));
    uint32_t l4=rneb(b.x-bfval(h4)), l5=rneb(b.y-bfval(h5));
    uint32_t l6=rneb(b.z-bfval(h6)), l7=rneb(b.w-bfval(h7));
    union { bf16x8 v; uint32_t u[4]; } H, L;
    H.u[0]=h0|(h1<<16); H.u[1]=h2|(h3<<16); H.u[2]=h4|(h5<<16); H.u[3]=h6|(h7<<16);
    L.u[0]=l0|(l1<<16); L.u[1]=l2|(l3<<16); L.u[2]=l4|(l5<<16); L.u[3]=l6|(l7<<16);
    Split8 r; r.hi = H.v; r.lo = L.v; return r;
}

// ---- prep: codebook -> swizzled split-bf16 image (per 16-code chunk, 4KB) + -0.5|c|^2 ----
__global__ __launch_bounds__(256) void vq_prep(const float* __restrict__ cb,
                                               uint8_t* __restrict__ stage,
                                               float* __restrict__ negcn) {
    int t = blockIdx.x * 256 + threadIdx.x;     // 0..32767, one per 8 floats
    int code = t >> 3, oct = t & 7;
    const float4* cp = (const float4*)(cb + (size_t)code * Dn + oct * 8);
    float4 f0 = cp[0], f1 = cp[1];
    Split8 s = split8(f0, f1);
    int j = code & 15, cc = code >> 4;
    uint32_t swz = (uint32_t)((j & 7) << 4);
    uint8_t* base = stage + (size_t)cc * 4096;
    *(bf16x8*)(base + (((unsigned)(j*256 +       oct*16)) ^ swz)) = s.hi;
    *(bf16x8*)(base + (((unsigned)(j*256 + 128 + oct*16)) ^ swz)) = s.lo;
    float n = f0.x*f0.x + f0.y*f0.y + f0.z*f0.z + f0.w*f0.w
            + f1.x*f1.x + f1.y*f1.y + f1.z*f1.z + f1.w*f1.w;
    n += __shfl_xor(n, 1); n += __shfl_xor(n, 2); n += __shfl_xor(n, 4);
    if (oct == 0) negcn[code] = -0.5f * n;
}

__global__ void vq_zero(float* __restrict__ loss_acc, int* __restrict__ flag_cnt) {
    *loss_acc = 0.0f; *flag_cnt = 0;
}

__global__ __launch_bounds__(256, 2) void vq_main(
    const float* __restrict__ x, const uint8_t* __restrict__ stage,
    const float* __restrict__ negcn, const float* __restrict__ cb,
    float* __restrict__ out, float* __restrict__ loss_acc,
    int* __restrict__ flag_cnt, int* __restrict__ flag_rows) {

    __shared__ __align__(16) uint8_t sbuf[2][4096];  // chunk double buffer
    __shared__ float sneg[Kn];                       // -0.5|c|^2
    __shared__ int sres[256];

    const int tid = threadIdx.x;
    const int lane = tid & 63, w = tid >> 6;
    const int g = lane >> 4, j = lane & 15;

    #pragma unroll
    for (int i = 0; i < 16; ++i) sneg[i*256 + tid] = negcn[i*256 + tid];

    // x rows -> resident A fragments (A layout: row=lane&15, k=(lane>>4)*8+e)
    const int rowbase = blockIdx.x * 256 + w * 64;
    bf16x8 ah[4][2], al[4][2];
    #pragma unroll
    for (int t = 0; t < 4; ++t) {
        const float* xr = x + (size_t)(rowbase + t*16 + j) * Dn + g*8;
        Split8 s0 = split8(*(const float4*)xr,        *(const float4*)(xr + 4));
        Split8 s1 = split8(*(const float4*)(xr + 32), *(const float4*)(xr + 36));
        ah[t][0] = s0.hi; al[t][0] = s0.lo;
        ah[t][1] = s1.hi; al[t][1] = s1.lo;
    }

    auto issue_chunk = [&](int c) {   // one global_load_lds_dwordx4 per lane
        const uint8_t* src = stage + ((size_t)c << 12) + (w << 10) + (lane << 4);
        uint8_t* dst = &sbuf[c & 1][w << 10];
        __builtin_amdgcn_global_load_lds((const __attribute__((address_space(1))) void*)src,
                                         (__attribute__((address_space(3))) void*)dst,
                                         16, 0, 0);
    };

    // B-fragment byte offsets (code j, features g*8.. of {ch0,ch1,cl0,cl1})
    const uint32_t swz = (uint32_t)((j & 7) << 4);
    const int o0 = (int)(((unsigned)(j*256 +   0 + g*16)) ^ swz);
    const int o1 = (int)(((unsigned)(j*256 +  64 + g*16)) ^ swz);
    const int o2 = (int)(((unsigned)(j*256 + 128 + g*16)) ^ swz);
    const int o3 = (int)(((unsigned)(j*256 + 192 + g*16)) ^ swz);

    float b1[16], b2[16]; int bch[16];
    #pragma unroll
    for (int s = 0; s < 16; ++s) { b1[s] = -3.4e38f; b2[s] = -3.4e38f; bch[s] = 0; }

    issue_chunk(0);
    __syncthreads();

    for (int c = 0; c < NCHUNK; ++c) {
        if (c + 1 < NCHUNK) issue_chunk(c + 1);
        const uint8_t* bb = sbuf[c & 1];
        bf16x8 B0 = *(const bf16x8*)(bb + o0);
        bf16x8 B1 = *(const bf16x8*)(bb + o1);
        bf16x8 B2 = *(const bf16x8*)(bb + o2);
        bf16x8 B3 = *(const bf16x8*)(bb + o3);
        float nc = sneg[c*16 + j];
        #pragma unroll
        for (int t = 0; t < 4; ++t) {
            f32x4 acc = {nc, nc, nc, nc};     // score = dot - 0.5|c|^2
            acc = __builtin_amdgcn_mfma_f32_16x16x32_bf16(ah[t][0], B0, acc, 0, 0, 0);
            acc = __builtin_amdgcn_mfma_f32_16x16x32_bf16(ah[t][1], B1, acc, 0, 0, 0);
            acc = __builtin_amdgcn_mfma_f32_16x16x32_bf16(al[t][0], B0, acc, 0, 0, 0);
            acc = __builtin_amdgcn_mfma_f32_16x16x32_bf16(al[t][1], B1, acc, 0, 0, 0);
            acc = __builtin_amdgcn_mfma_f32_16x16x32_bf16(ah[t][0], B2, acc, 0, 0, 0);
            acc = __builtin_amdgcn_mfma_f32_16x16x32_bf16(ah[t][1], B3, acc, 0, 0, 0);
            #pragma unroll
            for (int q = 0; q < 4; ++q) {
                int s = t*4 + q;
                float v = acc[q];
                float ob1 = b1[s];
                b2[s] = fmaxf(fminf(v, ob1), b2[s]);   // second-best (med3 pattern)
                bch[s] = (v > ob1) ? c : bch[s];
                b1[s] = fmaxf(v, ob1);
            }
        }
        __syncthreads();
    }

    // per-row merge across 16 col-slot lanes (D layout: row=(lane>>4)*4+q, col=lane&15)
    #pragma unroll
    for (int s = 0; s < 16; ++s) {
        float v1 = b1[s], v2 = b2[s];
        int kk = bch[s] * 16 + j;
        #pragma unroll
        for (int m = 1; m < 16; m <<= 1) {
            float p1 = __shfl_xor(v1, m);
            float p2 = __shfl_xor(v2, m);
            int pk = __shfl_xor(kk, m);
            v2 = fmaxf(fmaxf(v2, p2), fminf(v1, p1));
            bool take = (p1 > v1) || ((p1 == v1) && (pk < kk));
            v1 = take ? p1 : v1;
            kk = take ? pk : kk;
        }
        if (j == 0) {
            int flag = ((v1 - v2) < TAU_S) ? (int)0x80000000 : 0;
            sres[w*64 + (s >> 2)*16 + g*4 + (s & 3)] = kk | flag;
        }
    }
    __syncthreads();

    // epilogue: gather, straight-through out, loss; flag near-ties for rescan
    int pk = sres[tid];
    int idx = pk & 0x7FFFFFFF;
    bool flagged = pk < 0;
    size_t grow = (size_t)blockIdx.x * 256 + tid;
    const float4* xr2 = (const float4*)(x + grow * Dn);
    const float4* qr  = (const float4*)(cb + (size_t)idx * Dn);
    float4* orow = (float4*)(out + grow * Dn);
    float ls = 0.f;
    #pragma unroll
    for (int t2 = 0; t2 < 16; ++t2) {
        float4 xx = xr2[t2], qq = qr[t2];
        float dx = qq.x - xx.x, dy = qq.y - xx.y, dz = qq.z - xx.z, dw = qq.w - xx.w;
        float4 o; o.x = xx.x + dx; o.y = xx.y + dy; o.z = xx.z + dz; o.w = xx.w + dw;
        orow[t2] = o;
        ls = fmaf(dx, dx, ls); ls = fmaf(dy, dy, ls);
        ls = fmaf(dz, dz, ls); ls = fmaf(dw, dw, ls);
    }
    if (flagged) {
        ls = 0.f;
        int p = atomicAdd(flag_cnt, 1);
        flag_rows[p] = (int)grow;
    }
    #pragma unroll
    for (int m = 1; m < 64; m <<= 1) ls += __shfl_xor(ls, m);
    if (lane == 0) atomicAdd(loss_acc, ls);
}

// fp32 full rescan of flagged rows: ONE BLOCK PER ROW (grid-stride).
// 256 threads x 16 codes each; block argmin reduce; first 16 threads rewrite row.
__global__ __launch_bounds__(256) void vq_cleanup(
    const float* __restrict__ x, const float* __restrict__ cb,
    const float* __restrict__ negcn, const int* __restrict__ flag_cnt,
    const int* __restrict__ flag_rows, float* __restrict__ out,
    float* __restrict__ loss_acc) {
    __shared__ __align__(16) float sx[Dn];
    __shared__ float swb[4];
    __shared__ int   swi[4];
    const int tid = threadIdx.x;
    const int n = *flag_cnt;

    for (int r = blockIdx.x; r < n; r += gridDim.x) {
        const int row = flag_rows[r];
        __syncthreads();   // protect sx/swb from previous iteration readers
        if (tid < 16) ((float4*)sx)[tid] = ((const float4*)(x + (size_t)row * Dn))[tid];
        __syncthreads();

        float4 xv[16];
        #pragma unroll
        for (int t = 0; t < 16; ++t) xv[t] = ((const float4*)sx)[t];

        float best = 3.4e38f; int bidx = 0x7FFFFFFF;
        #pragma unroll 1
        for (int i = 0; i < Kn / 256; ++i) {          // 16 codes per thread
            const int k = i * 256 + tid;
            const float4* c4 = (const float4*)(cb + (size_t)k * Dn);
            float a0 = 0.f, a1 = 0.f, a2 = 0.f, a3 = 0.f;
            #pragma unroll
            for (int t = 0; t < 16; ++t) {
                float4 c = c4[t];
                a0 = fmaf(xv[t].x, c.x, a0);
                a1 = fmaf(xv[t].y, c.y, a1);
                a2 = fmaf(xv[t].z, c.z, a2);
                a3 = fmaf(xv[t].w, c.w, a3);
            }
            float cn = -2.0f * negcn[k];              // == |c|^2 exactly
            float d = fmaf(-2.0f, (a0 + a1) + (a2 + a3), cn);
            if (d < best || (d == best && k < bidx)) { best = d; bidx = k; }
        }
        // wave argmin (prefer lower k on ties -> np.argmin first occurrence)
        #pragma unroll
        for (int m = 1; m < 64; m <<= 1) {
            float pb = __shfl_xor(best, m);
            int   pi = __shfl_xor(bidx, m);
            if (pb < best || (pb == best && pi < bidx)) { best = pb; bidx = pi; }
        }
        if ((tid & 63) == 0) { swb[tid >> 6] = best; swi[tid >> 6] = bidx; }
        __syncthreads();
        float fb = swb[0]; int fi = swi[0];
        #pragma unroll
        for (int wv = 1; wv < 4; ++wv) {
            float pb = swb[wv]; int pi = swi[wv];
            if (pb < fb || (pb == fb && pi < fi)) { fb = pb; fi = pi; }
        }

        if (tid < 16) {
            float4 xx = ((const float4*)sx)[tid];
            float4 qq = ((const float4*)(cb + (size_t)fi * Dn))[tid];
            float dx = qq.x - xx.x, dy = qq.y - xx.y, dz = qq.z - xx.z, dw = qq.w - xx.w;
            float4 o; o.x = xx.x + dx; o.y = xx.y + dy; o.z = xx.z + dz; o.w = xx.w + dw;
            ((float4*)(out + (size_t)row * Dn))[tid] = o;
            float ls = dx*dx + dy*dy + dz*dz + dw*dw;
            ls += __shfl_xor(ls, 1); ls += __shfl_xor(ls, 2);
            ls += __shfl_xor(ls, 4); ls += __shfl_xor(ls, 8);
            if (tid == 0) atomicAdd(loss_acc, ls);
        }
    }
}

__global__ void vq_final(float* __restrict__ loss_acc) {
    *loss_acc = *loss_acc * (1.25f / (float)(Bn * Dn));
}

extern "C" void kernel_launch(void* const* d_in, const int* in_sizes, int n_in,
                              void* d_out, int out_size, void* d_ws, size_t ws_size,
                              hipStream_t stream) {
    const float* x  = (const float*)d_in[0];
    const float* cb = (const float*)d_in[1];
    float* out  = (float*)d_out;
    float* loss = out + (size_t)Bn * Dn;

    // ws layout: [negcn 16KB][stage 1MB][flag_cnt 4B][flag_rows 512KB] = ~1.6MB
    uint8_t* wsb = (uint8_t*)d_ws;
    float*   negcn     = (float*)wsb;
    uint8_t* stage     = wsb + 16384;
    int*     flag_cnt  = (int*)(wsb + 16384 + (size_t)NCHUNK * 4096);
    int*     flag_rows = flag_cnt + 1;

    vq_prep<<<128, 256, 0, stream>>>(cb, stage, negcn);
    vq_zero<<<1, 1, 0, stream>>>(loss, flag_cnt);
    vq_main<<<512, 256, 0, stream>>>(x, stage, negcn, cb, out, loss, flag_cnt, flag_rows);
    vq_cleanup<<<512, 256, 0, stream>>>(x, cb, negcn, flag_cnt, flag_rows, out, loss);
    vq_final<<<1, 1, 0, stream>>>(loss);
}

// Round 4
// 327.510 us; speedup vs baseline: 5.6940x; 1.4590x over previous
//
#include <hip/hip_runtime.h>
#include <stdint.h>

// VQ: B=131072 rows, K=4096 codes, D=64, fp32 in/out.
// out = [B*D floats quantized_st][1 float loss]
//
// bf16 split-precision MFMA distance search (3-product exact-split, score
// error <~1e-3), per-row top-2 tracking, fp64 full rescan of near-tie rows.
// Stage image is FRAGMENT-MAJOR so all ds_read_b128 are linear (conflict-free).
constexpr int Bn = 131072, Kn = 4096, Dn = 64;
constexpr int NCHUNK = 256;          // K / 16 codes per chunk
constexpr float TAU_S = 0.008f;      // score-gap flag threshold (~8x error bound)

typedef short bf16x8 __attribute__((ext_vector_type(8)));
typedef float f32x4  __attribute__((ext_vector_type(4)));

__device__ __forceinline__ uint32_t rneb(float f) {           // bf16 RNE bits
    uint32_t u = __float_as_uint(f);
    return (u + 0x7FFFu + ((u >> 16) & 1u)) >> 16;
}
__device__ __forceinline__ float bfval(uint32_t b) { return __uint_as_float(b << 16); }

struct Split8 { bf16x8 hi, lo; };
__device__ __forceinline__ Split8 split8(float4 a, float4 b) {
    uint32_t h0=rneb(a.x),h1=rneb(a.y),h2=rneb(a.z),h3=rneb(a.w);
    uint32_t h4=rneb(b.x),h5=rneb(b.y),h6=rneb(b.z),h7=rneb(b.w);
    uint32_t l0=rneb(a.x-bfval(h0)), l1=rneb(a.y-bfval(h1));
    uint32_t l2=rneb(a.z-bfval(h2)), l3=rneb(a.w-bfval(h3));
    uint32_t l4=rneb(b.x-bfval(h4)), l5=rneb(b.y-bfval(h5));
    uint32_t l6=rneb(b.z-bfval(h6)), l7=rneb(b.w-bfval(h7));
    union { bf16x8 v; uint32_t u[4]; } H, L;
    H.u[0]=h0|(h1<<16); H.u[1]=h2|(h3<<16); H.u[2]=h4|(h5<<16); H.u[3]=h6|(h7<<16);
    L.u[0]=l0|(l1<<16); L.u[1]=l2|(l3<<16); L.u[2]=l4|(l5<<16); L.u[3]=l6|(l7<<16);
    Split8 r; r.hi = H.v; r.lo = L.v; return r;
}

// ---- prep: codebook -> fragment-major split-bf16 image (4KB per 16-code chunk) ----
// chunk layout: [B0: 64 lanes x 16B][B1][B2][B3]; lane(j,g)=g*16+j holds code j,
// features g*8..g*8+7; B0/B1 = hi(0..31 / 32..63), B2/B3 = lo.
__global__ __launch_bounds__(256) void vq_prep(const float* __restrict__ cb,
                                               uint8_t* __restrict__ stage,
                                               float* __restrict__ negcn) {
    int t = blockIdx.x * 256 + threadIdx.x;     // 0..32767, one per 8 floats
    int code = t >> 3, oct = t & 7;
    const float4* cp = (const float4*)(cb + (size_t)code * Dn + oct * 8);
    float4 f0 = cp[0], f1 = cp[1];
    Split8 s = split8(f0, f1);
    int j = code & 15, cc = code >> 4;
    uint8_t* base = stage + (size_t)cc * 4096;
    int dsto = (((oct & 3) * 16 + j) << 4) + ((oct & 4) ? 1024 : 0);
    *(bf16x8*)(base + dsto)        = s.hi;
    *(bf16x8*)(base + 2048 + dsto) = s.lo;
    float n = f0.x*f0.x + f0.y*f0.y + f0.z*f0.z + f0.w*f0.w
            + f1.x*f1.x + f1.y*f1.y + f1.z*f1.z + f1.w*f1.w;
    n += __shfl_xor(n, 1); n += __shfl_xor(n, 2); n += __shfl_xor(n, 4);
    if (oct == 0) negcn[code] = -0.5f * n;
}

__global__ void vq_zero(float* __restrict__ loss_acc, int* __restrict__ flag_cnt) {
    *loss_acc = 0.0f; *flag_cnt = 0;
}

// 1024 blocks x 256 thr; 4 waves/block; 32 rows per wave (128 rows/block).
__global__ __launch_bounds__(256, 4) void vq_main(
    const float* __restrict__ x, const uint8_t* __restrict__ stage,
    const float* __restrict__ negcn, const float* __restrict__ cb,
    float* __restrict__ out, float* __restrict__ loss_acc,
    int* __restrict__ flag_cnt, int* __restrict__ flag_rows) {

    __shared__ __align__(16) uint8_t sbuf[2][4096];  // chunk double buffer
    __shared__ float sneg[Kn];                       // -0.5|c|^2
    __shared__ int sres[128];

    const int tid = threadIdx.x;
    const int lane = tid & 63, w = tid >> 6;
    const int g = lane >> 4, j = lane & 15;

    #pragma unroll
    for (int i = 0; i < 16; ++i) sneg[i*256 + tid] = negcn[i*256 + tid];

    // A fragments: 2 sub-tiles of 16 rows (A layout: row=lane&15, k=(lane>>4)*8+e)
    const int rowbase = blockIdx.x * 128 + w * 32;
    bf16x8 ah[2][2], al[2][2];
    #pragma unroll
    for (int t = 0; t < 2; ++t) {
        const float* xr = x + (size_t)(rowbase + t*16 + j) * Dn + g*8;
        Split8 s0 = split8(*(const float4*)xr,        *(const float4*)(xr + 4));
        Split8 s1 = split8(*(const float4*)(xr + 32), *(const float4*)(xr + 36));
        ah[t][0] = s0.hi; al[t][0] = s0.lo;
        ah[t][1] = s1.hi; al[t][1] = s1.lo;
    }

    auto issue_chunk = [&](int c) {   // one global_load_lds_dwordx4 per lane
        const uint8_t* src = stage + ((size_t)c << 12) + (w << 10) + (lane << 4);
        uint8_t* dst = &sbuf[c & 1][w << 10];
        __builtin_amdgcn_global_load_lds((const __attribute__((address_space(1))) void*)src,
                                         (__attribute__((address_space(3))) void*)dst,
                                         16, 0, 0);
    };

    float b1[8], b2[8]; int bch[8];
    #pragma unroll
    for (int s = 0; s < 8; ++s) { b1[s] = -3.4e38f; b2[s] = -3.4e38f; bch[s] = 0; }

    issue_chunk(0);
    __syncthreads();

    const int loff = lane << 4;
    for (int c = 0; c < NCHUNK; ++c) {
        if (c + 1 < NCHUNK) issue_chunk(c + 1);
        const uint8_t* bb = sbuf[c & 1];
        bf16x8 B0 = *(const bf16x8*)(bb + loff);           // linear: conflict-free
        bf16x8 B1 = *(const bf16x8*)(bb + 1024 + loff);
        bf16x8 B2 = *(const bf16x8*)(bb + 2048 + loff);
        bf16x8 B3 = *(const bf16x8*)(bb + 3072 + loff);
        float nc = sneg[c*16 + j];
        f32x4 a0 = {nc, nc, nc, nc}, a1 = {nc, nc, nc, nc};
        a0 = __builtin_amdgcn_mfma_f32_16x16x32_bf16(ah[0][0], B0, a0, 0, 0, 0);
        a1 = __builtin_amdgcn_mfma_f32_16x16x32_bf16(ah[1][0], B0, a1, 0, 0, 0);
        a0 = __builtin_amdgcn_mfma_f32_16x16x32_bf16(ah[0][1], B1, a0, 0, 0, 0);
        a1 = __builtin_amdgcn_mfma_f32_16x16x32_bf16(ah[1][1], B1, a1, 0, 0, 0);
        a0 = __builtin_amdgcn_mfma_f32_16x16x32_bf16(al[0][0], B0, a0, 0, 0, 0);
        a1 = __builtin_amdgcn_mfma_f32_16x16x32_bf16(al[1][0], B0, a1, 0, 0, 0);
        a0 = __builtin_amdgcn_mfma_f32_16x16x32_bf16(al[0][1], B1, a0, 0, 0, 0);
        a1 = __builtin_amdgcn_mfma_f32_16x16x32_bf16(al[1][1], B1, a1, 0, 0, 0);
        a0 = __builtin_amdgcn_mfma_f32_16x16x32_bf16(ah[0][0], B2, a0, 0, 0, 0);
        a1 = __builtin_amdgcn_mfma_f32_16x16x32_bf16(ah[1][0], B2, a1, 0, 0, 0);
        a0 = __builtin_amdgcn_mfma_f32_16x16x32_bf16(ah[0][1], B3, a0, 0, 0, 0);
        a1 = __builtin_amdgcn_mfma_f32_16x16x32_bf16(ah[1][1], B3, a1, 0, 0, 0);
        #pragma unroll
        for (int q = 0; q < 4; ++q) {
            float v = a0[q], ob = b1[q];
            b2[q]  = fmaxf(fminf(v, ob), b2[q]);
            bch[q] = (v > ob) ? c : bch[q];
            b1[q]  = fmaxf(v, ob);
        }
        #pragma unroll
        for (int q = 0; q < 4; ++q) {
            float v = a1[q], ob = b1[4+q];
            b2[4+q]  = fmaxf(fminf(v, ob), b2[4+q]);
            bch[4+q] = (v > ob) ? c : bch[4+q];
            b1[4+q]  = fmaxf(v, ob);
        }
        __syncthreads();
    }

    // per-row merge across the 16 code-lanes (D layout: row=(lane>>4)*4+q, col=lane&15)
    #pragma unroll
    for (int s = 0; s < 8; ++s) {
        float v1 = b1[s], v2 = b2[s];
        int kk = bch[s] * 16 + j;
        #pragma unroll
        for (int m = 1; m < 16; m <<= 1) {
            float p1 = __shfl_xor(v1, m);
            float p2 = __shfl_xor(v2, m);
            int pk = __shfl_xor(kk, m);
            v2 = fmaxf(fmaxf(v2, p2), fminf(v1, p1));
            bool take = (p1 > v1) || ((p1 == v1) && (pk < kk));
            v1 = take ? p1 : v1;
            kk = take ? pk : kk;
        }
        if (j == 0) {
            int flag = ((v1 - v2) < TAU_S) ? (int)0x80000000 : 0;
            sres[w*32 + (s >> 2)*16 + g*4 + (s & 3)] = kk | flag;
        }
    }
    __syncthreads();

    // epilogue: 2 threads per row (128 rows/block)
    const int r = tid >> 1, h = tid & 1;
    int pk = sres[r];
    int idx = pk & 0x7FFFFFFF;
    bool flagged = pk < 0;
    size_t grow = (size_t)blockIdx.x * 128 + r;
    const float4* xr2 = (const float4*)(x + grow * Dn) + h*8;
    const float4* qr  = (const float4*)(cb + (size_t)idx * Dn) + h*8;
    float4* orow = (float4*)(out + grow * Dn) + h*8;
    float ls = 0.f;
    #pragma unroll
    for (int t2 = 0; t2 < 8; ++t2) {
        float4 xx = xr2[t2], qq = qr[t2];
        float dx = qq.x - xx.x, dy = qq.y - xx.y, dz = qq.z - xx.z, dw = qq.w - xx.w;
        float4 o; o.x = xx.x + dx; o.y = xx.y + dy; o.z = xx.z + dz; o.w = xx.w + dw;
        orow[t2] = o;
        ls = fmaf(dx, dx, ls); ls = fmaf(dy, dy, ls);
        ls = fmaf(dz, dz, ls); ls = fmaf(dw, dw, ls);
    }
    if (flagged) {
        ls = 0.f;
        if (h == 0) { int p = atomicAdd(flag_cnt, 1); flag_rows[p] = (int)grow; }
    }
    #pragma unroll
    for (int m = 1; m < 64; m <<= 1) ls += __shfl_xor(ls, m);
    if (lane == 0) atomicAdd(loss_acc, ls);
}

// fp64 full rescan of flagged rows, 4 rows per block-iteration (codebook read shared).
__global__ __launch_bounds__(256) void vq_cleanup(
    const float* __restrict__ x, const float* __restrict__ cb,
    const int* __restrict__ flag_cnt, const int* __restrict__ flag_rows,
    float* __restrict__ out, float* __restrict__ loss_acc) {
    __shared__ double sxd[4][Dn];
    __shared__ double swb[4][4];
    __shared__ int    swi[4][4];
    const int tid = threadIdx.x;
    const int n = *flag_cnt;

    for (int it = blockIdx.x; it * 4 < n; it += gridDim.x) {
        const int base = it * 4;
        const int nr = min(4, n - base);
        __syncthreads();   // protect sxd/swb from previous iteration readers
        {
            int rr = tid >> 6, e = tid & 63;
            int row = flag_rows[base + ((rr < nr) ? rr : 0)];
            sxd[rr][e] = (double)x[(size_t)row * Dn + e];
        }
        __syncthreads();

        double best[4]; int bidx[4];
        #pragma unroll
        for (int r2 = 0; r2 < 4; ++r2) { best[r2] = 1.0e300; bidx[r2] = 0x7FFFFFFF; }

        #pragma unroll 1
        for (int i = 0; i < Kn / 256; ++i) {          // 16 codes per thread
            const int k = i * 256 + tid;
            const float* c4 = cb + (size_t)k * Dn;
            double cn = 0.0;
            double d0 = 0.0, d1 = 0.0, d2 = 0.0, d3 = 0.0;
            #pragma unroll 8
            for (int e = 0; e < Dn; ++e) {
                double ce = (double)c4[e];
                cn = fma(ce, ce, cn);
                d0 = fma(ce, sxd[0][e], d0);
                d1 = fma(ce, sxd[1][e], d1);
                d2 = fma(ce, sxd[2][e], d2);
                d3 = fma(ce, sxd[3][e], d3);
            }
            double dd[4] = { cn - 2.0*d0, cn - 2.0*d1, cn - 2.0*d2, cn - 2.0*d3 };
            #pragma unroll
            for (int r2 = 0; r2 < 4; ++r2)
                if (dd[r2] < best[r2] || (dd[r2] == best[r2] && k < bidx[r2])) {
                    best[r2] = dd[r2]; bidx[r2] = k;
                }
        }
        // wave argmin then cross-wave merge (first-occurrence ties)
        #pragma unroll
        for (int r2 = 0; r2 < 4; ++r2) {
            double bb = best[r2]; int bi = bidx[r2];
            #pragma unroll
            for (int m = 1; m < 64; m <<= 1) {
                double pb = __shfl_xor(bb, m);
                int    pi = __shfl_xor(bi, m);
                if (pb < bb || (pb == bb && pi < bi)) { bb = pb; bi = pi; }
            }
            if ((tid & 63) == 0) { swb[r2][tid >> 6] = bb; swi[r2][tid >> 6] = bi; }
        }
        __syncthreads();
        if (tid < 4) {
            double fb = swb[tid][0]; int fi = swi[tid][0];
            #pragma unroll
            for (int wv = 1; wv < 4; ++wv) {
                double pb = swb[tid][wv]; int pi = swi[tid][wv];
                if (pb < fb || (pb == fb && pi < fi)) { fb = pb; fi = pi; }
            }
            swi[tid][0] = fi;
        }
        __syncthreads();

        if (tid < 64) {
            int r2 = tid >> 4, q = tid & 15;
            if (r2 < nr) {
                int row = flag_rows[base + r2];
                int fi  = swi[r2][0];
                float4 xx = ((const float4*)(x + (size_t)row * Dn))[q];
                float4 qq = ((const float4*)(cb + (size_t)fi * Dn))[q];
                float dx = qq.x - xx.x, dy = qq.y - xx.y, dz = qq.z - xx.z, dw = qq.w - xx.w;
                float4 o; o.x = xx.x + dx; o.y = xx.y + dy; o.z = xx.z + dz; o.w = xx.w + dw;
                ((float4*)(out + (size_t)row * Dn))[q] = o;
                float ls = dx*dx + dy*dy + dz*dz + dw*dw;
                ls += __shfl_xor(ls, 1); ls += __shfl_xor(ls, 2);
                ls += __shfl_xor(ls, 4); ls += __shfl_xor(ls, 8);
                if (q == 0) atomicAdd(loss_acc, ls);
            }
        }
    }
}

__global__ void vq_final(float* __restrict__ loss_acc) {
    *loss_acc = *loss_acc * (1.25f / (float)(Bn * Dn));
}

extern "C" void kernel_launch(void* const* d_in, const int* in_sizes, int n_in,
                              void* d_out, int out_size, void* d_ws, size_t ws_size,
                              hipStream_t stream) {
    const float* x  = (const float*)d_in[0];
    const float* cb = (const float*)d_in[1];
    float* out  = (float*)d_out;
    float* loss = out + (size_t)Bn * Dn;

    // ws layout: [negcn 16KB][stage 1MB][flag_cnt 4B][flag_rows 512KB]
    uint8_t* wsb = (uint8_t*)d_ws;
    float*   negcn     = (float*)wsb;
    uint8_t* stage     = wsb + 16384;
    int*     flag_cnt  = (int*)(wsb + 16384 + (size_t)NCHUNK * 4096);
    int*     flag_rows = flag_cnt + 1;

    vq_prep<<<128, 256, 0, stream>>>(cb, stage, negcn);
    vq_zero<<<1, 1, 0, stream>>>(loss, flag_cnt);
    vq_main<<<Bn / 128, 256, 0, stream>>>(x, stage, negcn, cb, out, loss, flag_cnt, flag_rows);
    vq_cleanup<<<512, 256, 0, stream>>>(x, cb, flag_cnt, flag_rows, out, loss);
    vq_final<<<1, 1, 0, stream>>>(loss);
}

// Round 5
// 325.065 us; speedup vs baseline: 5.7369x; 1.0075x over previous
//
#include <hip/hip_runtime.h>
#include <stdint.h>

// VQ: B=131072 rows, K=4096 codes, D=64, fp32 in/out.
// out = [B*D floats quantized_st][1 float loss]
//
// bf16 split-precision MFMA distance search (3-product exact-split, score
// error <~1e-3), per-row top-2 tracking, fp64 full rescan of near-tie rows.
// K-loop uses a 4-deep LDS ring + counted vmcnt + raw s_barrier (T3/T4):
// prefetch loads stay in flight across barriers, never drained to 0 mid-loop.
constexpr int Bn = 131072, Kn = 4096, Dn = 64;
constexpr int NCHUNK = 256;          // K / 16 codes per chunk
constexpr float TAU_S = 0.008f;      // score-gap flag threshold (~8x error bound)

typedef short bf16x8 __attribute__((ext_vector_type(8)));
typedef float f32x4  __attribute__((ext_vector_type(4)));

__device__ __forceinline__ uint32_t rneb(float f) {           // bf16 RNE bits
    uint32_t u = __float_as_uint(f);
    return (u + 0x7FFFu + ((u >> 16) & 1u)) >> 16;
}
__device__ __forceinline__ float bfval(uint32_t b) { return __uint_as_float(b << 16); }

struct Split8 { bf16x8 hi, lo; };
__device__ __forceinline__ Split8 split8(float4 a, float4 b) {
    uint32_t h0=rneb(a.x),h1=rneb(a.y),h2=rneb(a.z),h3=rneb(a.w);
    uint32_t h4=rneb(b.x),h5=rneb(b.y),h6=rneb(b.z),h7=rneb(b.w);
    uint32_t l0=rneb(a.x-bfval(h0)), l1=rneb(a.y-bfval(h1));
    uint32_t l2=rneb(a.z-bfval(h2)), l3=rneb(a.w-bfval(h3));
    uint32_t l4=rneb(b.x-bfval(h4)), l5=rneb(b.y-bfval(h5));
    uint32_t l6=rneb(b.z-bfval(h6)), l7=rneb(b.w-bfval(h7));
    union { bf16x8 v; uint32_t u[4]; } H, L;
    H.u[0]=h0|(h1<<16); H.u[1]=h2|(h3<<16); H.u[2]=h4|(h5<<16); H.u[3]=h6|(h7<<16);
    L.u[0]=l0|(l1<<16); L.u[1]=l2|(l3<<16); L.u[2]=l4|(l5<<16); L.u[3]=l6|(l7<<16);
    Split8 r; r.hi = H.v; r.lo = L.v; return r;
}

// ---- prep: codebook -> fragment-major split-bf16 image (4KB per 16-code chunk) ----
// chunk layout: [B0: 64 lanes x 16B][B1][B2][B3]; lane(j,g)=g*16+j holds code j,
// features g*8..g*8+7; B0/B1 = hi(0..31 / 32..63), B2/B3 = lo.
__global__ __launch_bounds__(256) void vq_prep(const float* __restrict__ cb,
                                               uint8_t* __restrict__ stage,
                                               float* __restrict__ negcn) {
    int t = blockIdx.x * 256 + threadIdx.x;     // 0..32767, one per 8 floats
    int code = t >> 3, oct = t & 7;
    const float4* cp = (const float4*)(cb + (size_t)code * Dn + oct * 8);
    float4 f0 = cp[0], f1 = cp[1];
    Split8 s = split8(f0, f1);
    int j = code & 15, cc = code >> 4;
    uint8_t* base = stage + (size_t)cc * 4096;
    int dsto = (((oct & 3) * 16 + j) << 4) + ((oct & 4) ? 1024 : 0);
    *(bf16x8*)(base + dsto)        = s.hi;
    *(bf16x8*)(base + 2048 + dsto) = s.lo;
    float n = f0.x*f0.x + f0.y*f0.y + f0.z*f0.z + f0.w*f0.w
            + f1.x*f1.x + f1.y*f1.y + f1.z*f1.z + f1.w*f1.w;
    n += __shfl_xor(n, 1); n += __shfl_xor(n, 2); n += __shfl_xor(n, 4);
    if (oct == 0) negcn[code] = -0.5f * n;
}

__global__ void vq_zero(float* __restrict__ loss_acc, int* __restrict__ flag_cnt) {
    *loss_acc = 0.0f; *flag_cnt = 0;
}

// 1024 blocks x 256 thr; 4 waves/block; 32 rows per wave (128 rows/block).
__global__ __launch_bounds__(256, 4) void vq_main(
    const float* __restrict__ x, const uint8_t* __restrict__ stage,
    const float* __restrict__ negcn, const float* __restrict__ cb,
    float* __restrict__ out, float* __restrict__ loss_acc,
    int* __restrict__ flag_cnt, int* __restrict__ flag_rows) {

    __shared__ __align__(16) uint8_t sbuf[4][4096];  // 4-deep chunk ring
    __shared__ float sneg[Kn];                       // -0.5|c|^2
    __shared__ int sres[128];

    const int tid = threadIdx.x;
    const int lane = tid & 63, w = tid >> 6;
    const int g = lane >> 4, j = lane & 15;

    #pragma unroll
    for (int i = 0; i < 16; ++i) sneg[i*256 + tid] = negcn[i*256 + tid];

    // A fragments: 2 sub-tiles of 16 rows (A layout: row=lane&15, k=(lane>>4)*8+e)
    const int rowbase = blockIdx.x * 128 + w * 32;
    bf16x8 ah[2][2], al[2][2];
    #pragma unroll
    for (int t = 0; t < 2; ++t) {
        const float* xr = x + (size_t)(rowbase + t*16 + j) * Dn + g*8;
        Split8 s0 = split8(*(const float4*)xr,        *(const float4*)(xr + 4));
        Split8 s1 = split8(*(const float4*)(xr + 32), *(const float4*)(xr + 36));
        ah[t][0] = s0.hi; al[t][0] = s0.lo;
        ah[t][1] = s1.hi; al[t][1] = s1.lo;
    }

    auto issue_chunk = [&](int c) {   // one global_load_lds_dwordx4 per lane
        const uint8_t* src = stage + ((size_t)c << 12) + (w << 10) + (lane << 4);
        uint8_t* dst = &sbuf[c & 3][w << 10];
        __builtin_amdgcn_global_load_lds((const __attribute__((address_space(1))) void*)src,
                                         (__attribute__((address_space(3))) void*)dst,
                                         16, 0, 0);
    };

    float b1[8], b2[8]; int bch[8];
    #pragma unroll
    for (int s = 0; s < 8; ++s) { b1[s] = -3.4e38f; b2[s] = -3.4e38f; bch[s] = 0; }

    // full barrier once: sneg visible, then start the pipeline
    __syncthreads();
    issue_chunk(0); issue_chunk(1); issue_chunk(2);

    const int loff = lane << 4;

    // Per-chunk body. VMSTR: own outstanding stage-loads allowed to remain
    // in flight (chunk c's load must be complete). Loads for c+1,c+2 fly on.
#define VQ_BODY(VMSTR, DO_ISSUE, CIDX)                                        \
    {                                                                         \
        const int c_ = (CIDX);                                                \
        asm volatile("s_waitcnt " VMSTR ::: "memory");                        \
        __builtin_amdgcn_s_barrier();                                         \
        asm volatile("" ::: "memory");                                        \
        if (DO_ISSUE) issue_chunk(c_ + 3);                                    \
        const uint8_t* bb = sbuf[c_ & 3];                                     \
        bf16x8 B0 = *(const bf16x8*)(bb + loff);                              \
        bf16x8 B1 = *(const bf16x8*)(bb + 1024 + loff);                       \
        bf16x8 B2 = *(const bf16x8*)(bb + 2048 + loff);                       \
        bf16x8 B3 = *(const bf16x8*)(bb + 3072 + loff);                       \
        float nc = sneg[c_*16 + j];                                           \
        f32x4 a0 = {nc, nc, nc, nc}, a1 = {nc, nc, nc, nc};                   \
        __builtin_amdgcn_s_setprio(1);                                        \
        a0 = __builtin_amdgcn_mfma_f32_16x16x32_bf16(ah[0][0], B0, a0, 0, 0, 0); \
        a1 = __builtin_amdgcn_mfma_f32_16x16x32_bf16(ah[1][0], B0, a1, 0, 0, 0); \
        a0 = __builtin_amdgcn_mfma_f32_16x16x32_bf16(ah[0][1], B1, a0, 0, 0, 0); \
        a1 = __builtin_amdgcn_mfma_f32_16x16x32_bf16(ah[1][1], B1, a1, 0, 0, 0); \
        a0 = __builtin_amdgcn_mfma_f32_16x16x32_bf16(al[0][0], B0, a0, 0, 0, 0); \
        a1 = __builtin_amdgcn_mfma_f32_16x16x32_bf16(al[1][0], B0, a1, 0, 0, 0); \
        a0 = __builtin_amdgcn_mfma_f32_16x16x32_bf16(al[0][1], B1, a0, 0, 0, 0); \
        a1 = __builtin_amdgcn_mfma_f32_16x16x32_bf16(al[1][1], B1, a1, 0, 0, 0); \
        a0 = __builtin_amdgcn_mfma_f32_16x16x32_bf16(ah[0][0], B2, a0, 0, 0, 0); \
        a1 = __builtin_amdgcn_mfma_f32_16x16x32_bf16(ah[1][0], B2, a1, 0, 0, 0); \
        a0 = __builtin_amdgcn_mfma_f32_16x16x32_bf16(ah[0][1], B3, a0, 0, 0, 0); \
        a1 = __builtin_amdgcn_mfma_f32_16x16x32_bf16(ah[1][1], B3, a1, 0, 0, 0); \
        __builtin_amdgcn_s_setprio(0);                                        \
        _Pragma("unroll")                                                     \
        for (int q = 0; q < 4; ++q) {                                         \
            float v = a0[q], ob = b1[q];                                      \
            b2[q]  = fmaxf(fminf(v, ob), b2[q]);                              \
            bch[q] = (v > ob) ? c_ : bch[q];                                  \
            b1[q]  = fmaxf(v, ob);                                            \
        }                                                                     \
        _Pragma("unroll")                                                     \
        for (int q = 0; q < 4; ++q) {                                         \
            float v = a1[q], ob = b1[4+q];                                    \
            b2[4+q]  = fmaxf(fminf(v, ob), b2[4+q]);                          \
            bch[4+q] = (v > ob) ? c_ : bch[4+q];                              \
            b1[4+q]  = fmaxf(v, ob);                                          \
        }                                                                     \
    }

    #pragma unroll 1
    for (int c = 0; c < NCHUNK - 3; ++c) {      // c = 0..252, issues 3..255
        VQ_BODY("vmcnt(2)", true, c)
    }
    VQ_BODY("vmcnt(2)", false, NCHUNK - 3)      // c=253: {253,254,255} in flight
    VQ_BODY("vmcnt(1)", false, NCHUNK - 2)      // c=254
    VQ_BODY("vmcnt(0)", false, NCHUNK - 1)      // c=255
#undef VQ_BODY

    // per-row merge across the 16 code-lanes (D layout: row=(lane>>4)*4+q, col=lane&15)
    #pragma unroll
    for (int s = 0; s < 8; ++s) {
        float v1 = b1[s], v2 = b2[s];
        int kk = bch[s] * 16 + j;
        #pragma unroll
        for (int m = 1; m < 16; m <<= 1) {
            float p1 = __shfl_xor(v1, m);
            float p2 = __shfl_xor(v2, m);
            int pk = __shfl_xor(kk, m);
            v2 = fmaxf(fmaxf(v2, p2), fminf(v1, p1));
            bool take = (p1 > v1) || ((p1 == v1) && (pk < kk));
            v1 = take ? p1 : v1;
            kk = take ? pk : kk;
        }
        if (j == 0) {
            int flag = ((v1 - v2) < TAU_S) ? (int)0x80000000 : 0;
            sres[w*32 + (s >> 2)*16 + g*4 + (s & 3)] = kk | flag;
        }
    }
    __syncthreads();

    // epilogue: 2 threads per row (128 rows/block)
    const int r = tid >> 1, h = tid & 1;
    int pk = sres[r];
    int idx = pk & 0x7FFFFFFF;
    bool flagged = pk < 0;
    size_t grow = (size_t)blockIdx.x * 128 + r;
    const float4* xr2 = (const float4*)(x + grow * Dn) + h*8;
    const float4* qr  = (const float4*)(cb + (size_t)idx * Dn) + h*8;
    float4* orow = (float4*)(out + grow * Dn) + h*8;
    float ls = 0.f;
    #pragma unroll
    for (int t2 = 0; t2 < 8; ++t2) {
        float4 xx = xr2[t2], qq = qr[t2];
        float dx = qq.x - xx.x, dy = qq.y - xx.y, dz = qq.z - xx.z, dw = qq.w - xx.w;
        float4 o; o.x = xx.x + dx; o.y = xx.y + dy; o.z = xx.z + dz; o.w = xx.w + dw;
        orow[t2] = o;
        ls = fmaf(dx, dx, ls); ls = fmaf(dy, dy, ls);
        ls = fmaf(dz, dz, ls); ls = fmaf(dw, dw, ls);
    }
    if (flagged) {
        ls = 0.f;
        if (h == 0) { int p = atomicAdd(flag_cnt, 1); flag_rows[p] = (int)grow; }
    }
    #pragma unroll
    for (int m = 1; m < 64; m <<= 1) ls += __shfl_xor(ls, m);
    if (lane == 0) atomicAdd(loss_acc, ls);
}

// fp64 full rescan of flagged rows, 4 rows per block-iteration (codebook read shared).
__global__ __launch_bounds__(256) void vq_cleanup(
    const float* __restrict__ x, const float* __restrict__ cb,
    const int* __restrict__ flag_cnt, const int* __restrict__ flag_rows,
    float* __restrict__ out, float* __restrict__ loss_acc) {
    __shared__ double sxd[4][Dn];
    __shared__ double swb[4][4];
    __shared__ int    swi[4][4];
    const int tid = threadIdx.x;
    const int n = *flag_cnt;

    for (int it = blockIdx.x; it * 4 < n; it += gridDim.x) {
        const int base = it * 4;
        const int nr = min(4, n - base);
        __syncthreads();   // protect sxd/swb from previous iteration readers
        {
            int rr = tid >> 6, e = tid & 63;
            int row = flag_rows[base + ((rr < nr) ? rr : 0)];
            sxd[rr][e] = (double)x[(size_t)row * Dn + e];
        }
        __syncthreads();

        double best[4]; int bidx[4];
        #pragma unroll
        for (int r2 = 0; r2 < 4; ++r2) { best[r2] = 1.0e300; bidx[r2] = 0x7FFFFFFF; }

        #pragma unroll 1
        for (int i = 0; i < Kn / 256; ++i) {          // 16 codes per thread
            const int k = i * 256 + tid;
            const float* c4 = cb + (size_t)k * Dn;
            double cn = 0.0;
            double d0 = 0.0, d1 = 0.0, d2 = 0.0, d3 = 0.0;
            #pragma unroll 8
            for (int e = 0; e < Dn; ++e) {
                double ce = (double)c4[e];
                cn = fma(ce, ce, cn);
                d0 = fma(ce, sxd[0][e], d0);
                d1 = fma(ce, sxd[1][e], d1);
                d2 = fma(ce, sxd[2][e], d2);
                d3 = fma(ce, sxd[3][e], d3);
            }
            double dd[4] = { cn - 2.0*d0, cn - 2.0*d1, cn - 2.0*d2, cn - 2.0*d3 };
            #pragma unroll
            for (int r2 = 0; r2 < 4; ++r2)
                if (dd[r2] < best[r2] || (dd[r2] == best[r2] && k < bidx[r2])) {
                    best[r2] = dd[r2]; bidx[r2] = k;
                }
        }
        // wave argmin then cross-wave merge (first-occurrence ties)
        #pragma unroll
        for (int r2 = 0; r2 < 4; ++r2) {
            double bb = best[r2]; int bi = bidx[r2];
            #pragma unroll
            for (int m = 1; m < 64; m <<= 1) {
                double pb = __shfl_xor(bb, m);
                int    pi = __shfl_xor(bi, m);
                if (pb < bb || (pb == bb && pi < bi)) { bb = pb; bi = pi; }
            }
            if ((tid & 63) == 0) { swb[r2][tid >> 6] = bb; swi[r2][tid >> 6] = bi; }
        }
        __syncthreads();
        if (tid < 4) {
            double fb = swb[tid][0]; int fi = swi[tid][0];
            #pragma unroll
            for (int wv = 1; wv < 4; ++wv) {
                double pb = swb[tid][wv]; int pi = swi[tid][wv];
                if (pb < fb || (pb == fb && pi < fi)) { fb = pb; fi = pi; }
            }
            swi[tid][0] = fi;
        }
        __syncthreads();

        if (tid < 64) {
            int r2 = tid >> 4, q = tid & 15;
            if (r2 < nr) {
                int row = flag_rows[base + r2];
                int fi  = swi[r2][0];
                float4 xx = ((const float4*)(x + (size_t)row * Dn))[q];
                float4 qq = ((const float4*)(cb + (size_t)fi * Dn))[q];
                float dx = qq.x - xx.x, dy = qq.y - xx.y, dz = qq.z - xx.z, dw = qq.w - xx.w;
                float4 o; o.x = xx.x + dx; o.y = xx.y + dy; o.z = xx.z + dz; o.w = xx.w + dw;
                ((float4*)(out + (size_t)row * Dn))[q] = o;
                float ls = dx*dx + dy*dy + dz*dz + dw*dw;
                ls += __shfl_xor(ls, 1); ls += __shfl_xor(ls, 2);
                ls += __shfl_xor(ls, 4); ls += __shfl_xor(ls, 8);
                if (q == 0) atomicAdd(loss_acc, ls);
            }
        }
    }
}

__global__ void vq_final(float* __restrict__ loss_acc) {
    *loss_acc = *loss_acc * (1.25f / (float)(Bn * Dn));
}

extern "C" void kernel_launch(void* const* d_in, const int* in_sizes, int n_in,
                              void* d_out, int out_size, void* d_ws, size_t ws_size,
                              hipStream_t stream) {
    const float* x  = (const float*)d_in[0];
    const float* cb = (const float*)d_in[1];
    float* out  = (float*)d_out;
    float* loss = out + (size_t)Bn * Dn;

    // ws layout: [negcn 16KB][stage 1MB][flag_cnt 4B][flag_rows 512KB]
    uint8_t* wsb = (uint8_t*)d_ws;
    float*   negcn     = (float*)wsb;
    uint8_t* stage     = wsb + 16384;
    int*     flag_cnt  = (int*)(wsb + 16384 + (size_t)NCHUNK * 4096);
    int*     flag_rows = flag_cnt + 1;

    vq_prep<<<128, 256, 0, stream>>>(cb, stage, negcn);
    vq_zero<<<1, 1, 0, stream>>>(loss, flag_cnt);
    vq_main<<<Bn / 128, 256, 0, stream>>>(x, stage, negcn, cb, out, loss, flag_cnt, flag_rows);
    vq_cleanup<<<512, 256, 0, stream>>>(x, cb, flag_cnt, flag_rows, out, loss);
    vq_final<<<1, 1, 0, stream>>>(loss);
}

// Round 6
// 246.828 us; speedup vs baseline: 7.5553x; 1.3170x over previous
//
#include <hip/hip_runtime.h>
#include <stdint.h>

// VQ: B=131072 rows, K=4096 codes, D=64, fp32 in/out.
// out = [B*D floats quantized_st][1 float loss]
//
// bf16 split-precision MFMA distance search (3-product exact-split, score
// error <~1e-3), per-row top-2 tracking, fp64 full rescan of near-tie rows.
// K-loop: B fragments loaded DIRECTLY from L2-resident stage image into
// VGPRs, 4-chunk software pipeline, no LDS staging, no barriers, waves fully
// independent. 64 rows per wave amortize the per-wave B traffic (2 GB L2 total).
constexpr int Bn = 131072, Kn = 4096, Dn = 64;
constexpr int NCHUNK = 256;          // K / 16 codes per chunk
constexpr float TAU_S = 0.008f;      // score-gap flag threshold (~8x error bound)

typedef short bf16x8 __attribute__((ext_vector_type(8)));
typedef float f32x4  __attribute__((ext_vector_type(4)));

__device__ __forceinline__ uint32_t rneb(float f) {           // bf16 RNE bits
    uint32_t u = __float_as_uint(f);
    return (u + 0x7FFFu + ((u >> 16) & 1u)) >> 16;
}
__device__ __forceinline__ float bfval(uint32_t b) { return __uint_as_float(b << 16); }

struct Split8 { bf16x8 hi, lo; };
__device__ __forceinline__ Split8 split8(float4 a, float4 b) {
    uint32_t h0=rneb(a.x),h1=rneb(a.y),h2=rneb(a.z),h3=rneb(a.w);
    uint32_t h4=rneb(b.x),h5=rneb(b.y),h6=rneb(b.z),h7=rneb(b.w);
    uint32_t l0=rneb(a.x-bfval(h0)), l1=rneb(a.y-bfval(h1));
    uint32_t l2=rneb(a.z-bfval(h2)), l3=rneb(a.w-bfval(h3));
    uint32_t l4=rneb(b.x-bfval(h4)), l5=rneb(b.y-bfval(h5));
    uint32_t l6=rneb(b.z-bfval(h6)), l7=rneb(b.w-bfval(h7));
    union { bf16x8 v; uint32_t u[4]; } H, L;
    H.u[0]=h0|(h1<<16); H.u[1]=h2|(h3<<16); H.u[2]=h4|(h5<<16); H.u[3]=h6|(h7<<16);
    L.u[0]=l0|(l1<<16); L.u[1]=l2|(l3<<16); L.u[2]=l4|(l5<<16); L.u[3]=l6|(l7<<16);
    Split8 r; r.hi = H.v; r.lo = L.v; return r;
}

// ---- prep: codebook -> fragment-major split-bf16 image (4KB per 16-code chunk) ----
// chunk layout: [B0: 64 lanes x 16B][B1][B2][B3]; lane(j,g)=g*16+j holds code j,
// features g*8..g*8+7; B0/B1 = hi(0..31 / 32..63), B2/B3 = lo.
__global__ __launch_bounds__(256) void vq_prep(const float* __restrict__ cb,
                                               uint8_t* __restrict__ stage,
                                               float* __restrict__ negcn) {
    int t = blockIdx.x * 256 + threadIdx.x;     // 0..32767, one per 8 floats
    int code = t >> 3, oct = t & 7;
    const float4* cp = (const float4*)(cb + (size_t)code * Dn + oct * 8);
    float4 f0 = cp[0], f1 = cp[1];
    Split8 s = split8(f0, f1);
    int j = code & 15, cc = code >> 4;
    uint8_t* base = stage + (size_t)cc * 4096;
    int dsto = (((oct & 3) * 16 + j) << 4) + ((oct & 4) ? 1024 : 0);
    *(bf16x8*)(base + dsto)        = s.hi;
    *(bf16x8*)(base + 2048 + dsto) = s.lo;
    float n = f0.x*f0.x + f0.y*f0.y + f0.z*f0.z + f0.w*f0.w
            + f1.x*f1.x + f1.y*f1.y + f1.z*f1.z + f1.w*f1.w;
    n += __shfl_xor(n, 1); n += __shfl_xor(n, 2); n += __shfl_xor(n, 4);
    if (oct == 0) negcn[code] = -0.5f * n;
}

__global__ void vq_zero(float* __restrict__ loss_acc, int* __restrict__ flag_cnt) {
    *loss_acc = 0.0f; *flag_cnt = 0;
}

// 512 blocks x 256 thr; 4 waves/block; 64 rows per wave (256 rows/block).
__global__ __launch_bounds__(256, 2) void vq_main(
    const float* __restrict__ x, const uint8_t* __restrict__ stage,
    const float* __restrict__ negcn, const float* __restrict__ cb,
    float* __restrict__ out, float* __restrict__ loss_acc,
    int* __restrict__ flag_cnt, int* __restrict__ flag_rows) {

    __shared__ float sneg[Kn];                       // -0.5|c|^2
    __shared__ int sres[256];

    const int tid = threadIdx.x;
    const int lane = tid & 63, w = tid >> 6;
    const int g = lane >> 4, j = lane & 15;

    #pragma unroll
    for (int i = 0; i < 16; ++i) sneg[i*256 + tid] = negcn[i*256 + tid];

    // A fragments: 4 sub-tiles of 16 rows (A layout: row=lane&15, k=(lane>>4)*8+e)
    const int rowbase = blockIdx.x * 256 + w * 64;
    bf16x8 ah[4][2], al[4][2];
    #pragma unroll
    for (int t = 0; t < 4; ++t) {
        const float* xr = x + (size_t)(rowbase + t*16 + j) * Dn + g*8;
        Split8 s0 = split8(*(const float4*)xr,        *(const float4*)(xr + 4));
        Split8 s1 = split8(*(const float4*)(xr + 32), *(const float4*)(xr + 36));
        ah[t][0] = s0.hi; al[t][0] = s0.lo;
        ah[t][1] = s1.hi; al[t][1] = s1.lo;
    }

    float b1[16], b2[16]; int bch[16];
    #pragma unroll
    for (int s = 0; s < 16; ++s) { b1[s] = -3.4e38f; b2[s] = -3.4e38f; bch[s] = 0; }

    // 4-deep register prefetch of B fragments straight from L2 (no LDS, no barriers)
    const uint8_t* sp = stage + (lane << 4);
    bf16x8 Bf[4][4];
    #pragma unroll
    for (int p = 0; p < 4; ++p) {
        const uint8_t* bbp = sp + (size_t)p * 4096;
        Bf[p][0] = *(const bf16x8*)(bbp);
        Bf[p][1] = *(const bf16x8*)(bbp + 1024);
        Bf[p][2] = *(const bf16x8*)(bbp + 2048);
        Bf[p][3] = *(const bf16x8*)(bbp + 3072);
    }
    __syncthreads();     // sneg visible (only barrier before epilogue)

#define CHUNK_BODY(P, C, RELOAD)                                              \
    {                                                                         \
        const int c_ = (C);                                                   \
        bf16x8 B0 = Bf[P][0], B1 = Bf[P][1], B2 = Bf[P][2], B3 = Bf[P][3];    \
        float nc = sneg[(c_ << 4) + j];                                       \
        f32x4 a0 = {nc,nc,nc,nc}, a1 = {nc,nc,nc,nc};                         \
        f32x4 a2 = {nc,nc,nc,nc}, a3 = {nc,nc,nc,nc};                         \
        a0 = __builtin_amdgcn_mfma_f32_16x16x32_bf16(ah[0][0], B0, a0, 0,0,0);\
        a1 = __builtin_amdgcn_mfma_f32_16x16x32_bf16(ah[1][0], B0, a1, 0,0,0);\
        a2 = __builtin_amdgcn_mfma_f32_16x16x32_bf16(ah[2][0], B0, a2, 0,0,0);\
        a3 = __builtin_amdgcn_mfma_f32_16x16x32_bf16(ah[3][0], B0, a3, 0,0,0);\
        a0 = __builtin_amdgcn_mfma_f32_16x16x32_bf16(ah[0][1], B1, a0, 0,0,0);\
        a1 = __builtin_amdgcn_mfma_f32_16x16x32_bf16(ah[1][1], B1, a1, 0,0,0);\
        a2 = __builtin_amdgcn_mfma_f32_16x16x32_bf16(ah[2][1], B1, a2, 0,0,0);\
        a3 = __builtin_amdgcn_mfma_f32_16x16x32_bf16(ah[3][1], B1, a3, 0,0,0);\
        a0 = __builtin_amdgcn_mfma_f32_16x16x32_bf16(al[0][0], B0, a0, 0,0,0);\
        a1 = __builtin_amdgcn_mfma_f32_16x16x32_bf16(al[1][0], B0, a1, 0,0,0);\
        a2 = __builtin_amdgcn_mfma_f32_16x16x32_bf16(al[2][0], B0, a2, 0,0,0);\
        a3 = __builtin_amdgcn_mfma_f32_16x16x32_bf16(al[3][0], B0, a3, 0,0,0);\
        a0 = __builtin_amdgcn_mfma_f32_16x16x32_bf16(al[0][1], B1, a0, 0,0,0);\
        a1 = __builtin_amdgcn_mfma_f32_16x16x32_bf16(al[1][1], B1, a1, 0,0,0);\
        a2 = __builtin_amdgcn_mfma_f32_16x16x32_bf16(al[2][1], B1, a2, 0,0,0);\
        a3 = __builtin_amdgcn_mfma_f32_16x16x32_bf16(al[3][1], B1, a3, 0,0,0);\
        a0 = __builtin_amdgcn_mfma_f32_16x16x32_bf16(ah[0][0], B2, a0, 0,0,0);\
        a1 = __builtin_amdgcn_mfma_f32_16x16x32_bf16(ah[1][0], B2, a1, 0,0,0);\
        a2 = __builtin_amdgcn_mfma_f32_16x16x32_bf16(ah[2][0], B2, a2, 0,0,0);\
        a3 = __builtin_amdgcn_mfma_f32_16x16x32_bf16(ah[3][0], B2, a3, 0,0,0);\
        a0 = __builtin_amdgcn_mfma_f32_16x16x32_bf16(ah[0][1], B3, a0, 0,0,0);\
        a1 = __builtin_amdgcn_mfma_f32_16x16x32_bf16(ah[1][1], B3, a1, 0,0,0);\
        a2 = __builtin_amdgcn_mfma_f32_16x16x32_bf16(ah[2][1], B3, a2, 0,0,0);\
        a3 = __builtin_amdgcn_mfma_f32_16x16x32_bf16(ah[3][1], B3, a3, 0,0,0);\
        if (RELOAD) {   /* prefetch chunk c_+4 into this slot */              \
            const uint8_t* nb = sp + ((size_t)(c_ + 4) << 12);                \
            Bf[P][0] = *(const bf16x8*)(nb);                                  \
            Bf[P][1] = *(const bf16x8*)(nb + 1024);                           \
            Bf[P][2] = *(const bf16x8*)(nb + 2048);                           \
            Bf[P][3] = *(const bf16x8*)(nb + 3072);                           \
        }                                                                     \
        f32x4 aa[4] = {a0, a1, a2, a3};                                       \
        _Pragma("unroll")                                                     \
        for (int t = 0; t < 4; ++t) {                                         \
            _Pragma("unroll")                                                 \
            for (int q = 0; q < 4; ++q) {                                     \
                int s = t*4 + q;                                              \
                float v = aa[t][q], ob = b1[s];                               \
                b2[s]  = fmaxf(fminf(v, ob), b2[s]);                          \
                bch[s] = (v > ob) ? c_ : bch[s];                              \
                b1[s]  = fmaxf(v, ob);                                        \
            }                                                                 \
        }                                                                     \
    }

    #pragma unroll 1
    for (int c4 = 0; c4 < NCHUNK - 4; c4 += 4) {
        CHUNK_BODY(0, c4 + 0, true)
        CHUNK_BODY(1, c4 + 1, true)
        CHUNK_BODY(2, c4 + 2, true)
        CHUNK_BODY(3, c4 + 3, true)
    }
    CHUNK_BODY(0, NCHUNK - 4, false)
    CHUNK_BODY(1, NCHUNK - 3, false)
    CHUNK_BODY(2, NCHUNK - 2, false)
    CHUNK_BODY(3, NCHUNK - 1, false)
#undef CHUNK_BODY

    // per-row merge across the 16 code-lanes (D layout: row=(lane>>4)*4+q, col=lane&15)
    #pragma unroll
    for (int s = 0; s < 16; ++s) {
        float v1 = b1[s], v2 = b2[s];
        int kk = bch[s] * 16 + j;
        #pragma unroll
        for (int m = 1; m < 16; m <<= 1) {
            float p1 = __shfl_xor(v1, m);
            float p2 = __shfl_xor(v2, m);
            int pk = __shfl_xor(kk, m);
            v2 = fmaxf(fmaxf(v2, p2), fminf(v1, p1));
            bool take = (p1 > v1) || ((p1 == v1) && (pk < kk));
            v1 = take ? p1 : v1;
            kk = take ? pk : kk;
        }
        if (j == 0) {
            int flag = ((v1 - v2) < TAU_S) ? (int)0x80000000 : 0;
            sres[w*64 + (s >> 2)*16 + g*4 + (s & 3)] = kk | flag;
        }
    }
    __syncthreads();

    // epilogue: fully coalesced; f enumerates (row, float4) pairs
    float ls = 0.f;
    const size_t blockrow = (size_t)blockIdx.x * 256;
    #pragma unroll 1
    for (int it = 0; it < 16; ++it) {
        int f = it * 256 + tid;
        int r = f >> 4, q = f & 15;
        int pk = sres[r];
        int idx = pk & 0x7FFFFFFF;
        bool flagged = pk < 0;
        size_t grow = blockrow + r;
        float4 xx = ((const float4*)(x + grow * Dn))[q];
        float4 qq = ((const float4*)(cb + (size_t)idx * Dn))[q];
        float dx = qq.x - xx.x, dy = qq.y - xx.y, dz = qq.z - xx.z, dw = qq.w - xx.w;
        float4 o; o.x = xx.x + dx; o.y = xx.y + dy; o.z = xx.z + dz; o.w = xx.w + dw;
        ((float4*)(out + grow * Dn))[q] = o;
        if (flagged) {
            if (q == 0) { int p = atomicAdd(flag_cnt, 1); flag_rows[p] = (int)grow; }
        } else {
            ls = fmaf(dx, dx, ls); ls = fmaf(dy, dy, ls);
            ls = fmaf(dz, dz, ls); ls = fmaf(dw, dw, ls);
        }
    }
    #pragma unroll
    for (int m = 1; m < 64; m <<= 1) ls += __shfl_xor(ls, m);
    if (lane == 0) atomicAdd(loss_acc, ls);
}

// fp64 full rescan of flagged rows, 4 rows per block-iteration (codebook read shared).
__global__ __launch_bounds__(256) void vq_cleanup(
    const float* __restrict__ x, const float* __restrict__ cb,
    const int* __restrict__ flag_cnt, const int* __restrict__ flag_rows,
    float* __restrict__ out, float* __restrict__ loss_acc) {
    __shared__ double sxd[4][Dn];
    __shared__ double swb[4][4];
    __shared__ int    swi[4][4];
    const int tid = threadIdx.x;
    const int n = *flag_cnt;

    for (int it = blockIdx.x; it * 4 < n; it += gridDim.x) {
        const int base = it * 4;
        const int nr = min(4, n - base);
        __syncthreads();   // protect sxd/swb from previous iteration readers
        {
            int rr = tid >> 6, e = tid & 63;
            int row = flag_rows[base + ((rr < nr) ? rr : 0)];
            sxd[rr][e] = (double)x[(size_t)row * Dn + e];
        }
        __syncthreads();

        double best[4]; int bidx[4];
        #pragma unroll
        for (int r2 = 0; r2 < 4; ++r2) { best[r2] = 1.0e300; bidx[r2] = 0x7FFFFFFF; }

        #pragma unroll 1
        for (int i = 0; i < Kn / 256; ++i) {          // 16 codes per thread
            const int k = i * 256 + tid;
            const float* c4 = cb + (size_t)k * Dn;
            double cn = 0.0;
            double d0 = 0.0, d1 = 0.0, d2 = 0.0, d3 = 0.0;
            #pragma unroll 8
            for (int e = 0; e < Dn; ++e) {
                double ce = (double)c4[e];
                cn = fma(ce, ce, cn);
                d0 = fma(ce, sxd[0][e], d0);
                d1 = fma(ce, sxd[1][e], d1);
                d2 = fma(ce, sxd[2][e], d2);
                d3 = fma(ce, sxd[3][e], d3);
            }
            double dd[4] = { cn - 2.0*d0, cn - 2.0*d1, cn - 2.0*d2, cn - 2.0*d3 };
            #pragma unroll
            for (int r2 = 0; r2 < 4; ++r2)
                if (dd[r2] < best[r2] || (dd[r2] == best[r2] && k < bidx[r2])) {
                    best[r2] = dd[r2]; bidx[r2] = k;
                }
        }
        // wave argmin then cross-wave merge (first-occurrence ties)
        #pragma unroll
        for (int r2 = 0; r2 < 4; ++r2) {
            double bb = best[r2]; int bi = bidx[r2];
            #pragma unroll
            for (int m = 1; m < 64; m <<= 1) {
                double pb = __shfl_xor(bb, m);
                int    pi = __shfl_xor(bi, m);
                if (pb < bb || (pb == bb && pi < bi)) { bb = pb; bi = pi; }
            }
            if ((tid & 63) == 0) { swb[r2][tid >> 6] = bb; swi[r2][tid >> 6] = bi; }
        }
        __syncthreads();
        if (tid < 4) {
            double fb = swb[tid][0]; int fi = swi[tid][0];
            #pragma unroll
            for (int wv = 1; wv < 4; ++wv) {
                double pb = swb[tid][wv]; int pi = swi[tid][wv];
                if (pb < fb || (pb == fb && pi < fi)) { fb = pb; fi = pi; }
            }
            swi[tid][0] = fi;
        }
        __syncthreads();

        if (tid < 64) {
            int r2 = tid >> 4, q = tid & 15;
            if (r2 < nr) {
                int row = flag_rows[base + r2];
                int fi  = swi[r2][0];
                float4 xx = ((const float4*)(x + (size_t)row * Dn))[q];
                float4 qq = ((const float4*)(cb + (size_t)fi * Dn))[q];
                float dx = qq.x - xx.x, dy = qq.y - xx.y, dz = qq.z - xx.z, dw = qq.w - xx.w;
                float4 o; o.x = xx.x + dx; o.y = xx.y + dy; o.z = xx.z + dz; o.w = xx.w + dw;
                ((float4*)(out + (size_t)row * Dn))[q] = o;
                float ls = dx*dx + dy*dy + dz*dz + dw*dw;
                ls += __shfl_xor(ls, 1); ls += __shfl_xor(ls, 2);
                ls += __shfl_xor(ls, 4); ls += __shfl_xor(ls, 8);
                if (q == 0) atomicAdd(loss_acc, ls);
            }
        }
    }
}

__global__ void vq_final(float* __restrict__ loss_acc) {
    *loss_acc = *loss_acc * (1.25f / (float)(Bn * Dn));
}

extern "C" void kernel_launch(void* const* d_in, const int* in_sizes, int n_in,
                              void* d_out, int out_size, void* d_ws, size_t ws_size,
                              hipStream_t stream) {
    const float* x  = (const float*)d_in[0];
    const float* cb = (const float*)d_in[1];
    float* out  = (float*)d_out;
    float* loss = out + (size_t)Bn * Dn;

    // ws layout: [negcn 16KB][stage 1MB][flag_cnt 4B][flag_rows 512KB]
    uint8_t* wsb = (uint8_t*)d_ws;
    float*   negcn     = (float*)wsb;
    uint8_t* stage     = wsb + 16384;
    int*     flag_cnt  = (int*)(wsb + 16384 + (size_t)NCHUNK * 4096);
    int*     flag_rows = flag_cnt + 1;

    vq_prep<<<128, 256, 0, stream>>>(cb, stage, negcn);
    vq_zero<<<1, 1, 0, stream>>>(loss, flag_cnt);
    vq_main<<<Bn / 256, 256, 0, stream>>>(x, stage, negcn, cb, out, loss, flag_cnt, flag_rows);
    vq_cleanup<<<512, 256, 0, stream>>>(x, cb, flag_cnt, flag_rows, out, loss);
    vq_final<<<1, 1, 0, stream>>>(loss);
}